// Round 4
// baseline (2562.888 us; speedup 1.0000x reference)
//
#include <hip/hip_runtime.h>
#include <math.h>

#define NNODES 100000
#define NEDGES 1600000
#define NPOS   4096      // 32 seqs * 128 steps
#define NSEQ   32
#define TSTEPS 128

typedef float f32x4 __attribute__((ext_vector_type(4)));

// ---- ws layout (bytes) ----
#define OFF_SLOT   0          // int[100000]  (dead after k_pregemm)
#define OFF_AGG    400128     // float[4096*128]
#define OFF_CNT    2497280    // float[4096]
#define OFF_WF     2513664    // float[1024*128]
#define OFF_BIASF  3037952    // float[1024]
#define OFF_PREG   3042048    // float[128][32s][8m][4q][32d]
#define OFF_HS     19819264   // float[129][32][256]

// ---------------- init ----------------
__global__ void k_init(int* slotmap, float* agg, float* cnt, float* hs0) {
  int i = blockIdx.x * blockDim.x + threadIdx.x;
  int stride = gridDim.x * blockDim.x;
  for (int idx = i; idx < 4096 * 128; idx += stride) agg[idx] = 0.f;
  for (int idx = i; idx < NNODES; idx += stride) slotmap[idx] = -1;
  for (int idx = i; idx < 4096; idx += stride) cnt[idx] = 0.f;
  for (int idx = i; idx < 8192; idx += stride) hs0[idx] = 0.f;
}

// ---------------- mark needed nodes ----------------
__global__ void k_mark(const int* __restrict__ input_ids, int* __restrict__ slotmap) {
  int p = blockIdx.x * blockDim.x + threadIdx.x;
  if (p < NPOS) atomicCAS(&slotmap[input_ids[p]], -1, p);
}

// ---------------- edge pass: masked segment-sum ----------------
__global__ void k_edge(const int* __restrict__ src, const int* __restrict__ dst,
                       const float* __restrict__ ev, const float* __restrict__ emb,
                       const int* __restrict__ slotmap,
                       float* __restrict__ agg, float* __restrict__ cnt) {
  int e = blockIdx.x * 256 + threadIdx.x;
  int lane = threadIdx.x & 63;
  int d = dst[e];
  int slot = slotmap[d];
  int sn = 0; float vv = 0.f;
  if (slot >= 0) { sn = src[e]; vv = ev[e]; }
  unsigned long long m = __ballot(slot >= 0);
  while (m) {
    int j = __ffsll(m) - 1;
    m &= m - 1;
    int sl = __shfl(slot, j);
    int s2 = __shfl(sn, j);
    float v = __shfl(vv, j);
    float2 em = *(const float2*)&emb[(size_t)s2 * 128 + 2 * lane];
    atomicAdd(&agg[sl * 128 + 2 * lane],     em.x * v);
    atomicAdd(&agg[sl * 128 + 2 * lane + 1], em.y * v);
    if (lane == 0) atomicAdd(&cnt[sl], 1.f);
  }
}

// ---------------- divide by count ----------------
__global__ void k_div(float* __restrict__ agg, const float* __restrict__ cnt) {
  int i = blockIdx.x * blockDim.x + threadIdx.x;
  agg[i] /= fmaxf(cnt[i >> 7], 1.f);
}

// ---------------- fuse W_f = w_ih @ W1, bias_f ----------------
__global__ void k_fuse(const float* __restrict__ w_ih, const float* __restrict__ W1,
                       const float* __restrict__ b1, const float* __restrict__ b_ih,
                       const float* __restrict__ b_hh,
                       float* __restrict__ Wf, float* __restrict__ bf) {
  int row = blockIdx.x;
  int e = threadIdx.x;
  float acc = 0.f;
  for (int m2 = 0; m2 < 256; ++m2) acc += w_ih[row * 256 + m2] * W1[m2 * 128 + e];
  Wf[row * 128 + e] = acc;
  if (e == 0) {
    float bacc = b_ih[row] + b_hh[row];
    for (int m2 = 0; m2 < 256; ++m2) bacc += w_ih[row * 256 + m2] * b1[m2];
    bf[row] = bacc;
  }
}

// ---------------- pre-gates GEMM: preg[t][s][m][q][d] ----------------
__global__ __launch_bounds__(256, 2) void k_pregemm(
    const float* __restrict__ hnode, const float* __restrict__ Wf,
    const float* __restrict__ bf, const int* __restrict__ slotmap,
    const int* __restrict__ input_ids, float* __restrict__ preg) {
  __shared__ float Ash[64][132];
  __shared__ float Bsh[64][132];
  __shared__ int slots[64];
  int tid = threadIdx.x;
  int bm = (blockIdx.x & 63) * 64;
  int bn = (blockIdx.x >> 6) * 64;
  if (tid < 64) slots[tid] = slotmap[input_ids[bm + tid]];
  __syncthreads();
#pragma unroll
  for (int i = 0; i < 8; ++i) {
    int idx = tid + 256 * i;
    int r = idx >> 5, c = idx & 31;
    *(float4*)&Ash[r][c * 4] = *(const float4*)&hnode[slots[r] * 128 + c * 4];
    *(float4*)&Bsh[r][c * 4] = *(const float4*)&Wf[(bn + r) * 128 + c * 4];
  }
  __syncthreads();
  int tx = tid & 15, ty = tid >> 4;
  float acc[4][4] = {};
  for (int k = 0; k < 128; k += 4) {
    float4 a[4], bb[4];
#pragma unroll
    for (int i = 0; i < 4; ++i) a[i] = *(const float4*)&Ash[tx + 16 * i][k];
#pragma unroll
    for (int j = 0; j < 4; ++j) bb[j] = *(const float4*)&Bsh[ty + 16 * j][k];
#pragma unroll
    for (int i = 0; i < 4; ++i)
#pragma unroll
      for (int j = 0; j < 4; ++j)
        acc[i][j] += a[i].x * bb[j].x + a[i].y * bb[j].y + a[i].z * bb[j].z + a[i].w * bb[j].w;
  }
#pragma unroll
  for (int j = 0; j < 4; ++j) {
    int row = bn + ty + 16 * j;
    float bias = bf[row];
    int q  = row >> 8;
    int mm = (row >> 5) & 7;
    int dl = row & 31;
#pragma unroll
    for (int i = 0; i < 4; ++i) {
      int p = bm + tx + 16 * i;
      int s = p >> 7, tt = p & 127;
      preg[(((size_t)(tt * 32 + s) * 8 + mm) * 4 + q) * 32 + dl] = acc[i][j] + bias;
    }
  }
}

// ---------------- LSTM: ONE sequence per 1024-thread block, LDS exchange ----------------
// Rounds 0-3 proved every cross-workgroup signaling path (agent load, sc0 load,
// L2 atomic) costs ~2us/step round trip at the device coherence point. So: no
// cross-block exchange at all. Each block owns one sequence; h lives in LDS;
// the per-step sync is __syncthreads (~100ns). Thread (kseg=tid>>8, d=tid&255)
// holds w_hh rows {q*256+d : q=0..3}, k-slice [kseg*64, kseg*64+64) in 256 VGPRs
// and computes 4 partial gate dots; partials reduce across the 4 ksegs via LDS.
// h reads are wave-uniform addresses (kseg constant per wave) => LDS broadcast.
// VALU floor: 262144 FMA/step / 128 FMA/cyc/CU = 853ns/step.
__global__ __launch_bounds__(1024) void k_lstm(
    const float* __restrict__ w_hh, const float* __restrict__ preg,
    float* __restrict__ hs) {
  __shared__ float h_cur[256];
  __shared__ float accbuf[4 * 256 * 4];   // [kseg][d][gate]
  const int tid  = threadIdx.x;
  const int s    = blockIdx.x;
  const int kseg = tid >> 8;
  const int d    = tid & 255;
  const bool owner = (kseg == 0);

  // register-resident weights: 4 gate-rows x 64 k = 64 f32x4 (256 VGPR)
  f32x4 wv[4][16];
#pragma unroll
  for (int q = 0; q < 4; ++q) {
    const float* wp = w_hh + (size_t)(q * 256 + d) * 256 + kseg * 64;
#pragma unroll
    for (int i = 0; i < 16; ++i) wv[q][i] = *(const f32x4*)(wp + 4 * i);
  }

  if (tid < 256) h_cur[tid] = 0.f;
  float c_st = 0.f;
  __syncthreads();

  const float* pregs = preg + (size_t)s * 1024 + (d >> 5) * 128 + (d & 31);

  for (int t = 0; t < TSTEPS; ++t) {
    // pre-gates for this step (owners only); issued early, used after barrier
    float pg0 = 0.f, pg1 = 0.f, pg2 = 0.f, pg3 = 0.f;
    if (owner) {
      const float* pb = pregs + (size_t)t * 32768;   // t*32*1024 floats
      pg0 = pb[0]; pg1 = pb[32]; pg2 = pb[64]; pg3 = pb[96];
    }
    // partial dots over this thread's 64-k slice (LDS broadcast reads)
    const f32x4* hseg = (const f32x4*)(h_cur + kseg * 64);
    f32x4 a0 = {0.f,0.f,0.f,0.f}, a1 = a0, a2 = a0, a3 = a0;
#pragma unroll
    for (int i = 0; i < 16; ++i) {
      f32x4 hv = hseg[i];
      a0 += wv[0][i] * hv;
      a1 += wv[1][i] * hv;
      a2 += wv[2][i] * hv;
      a3 += wv[3][i] * hv;
    }
    f32x4 r;
    r.x = (a0.x + a0.y) + (a0.z + a0.w);
    r.y = (a1.x + a1.y) + (a1.z + a1.w);
    r.z = (a2.x + a2.y) + (a2.z + a2.w);
    r.w = (a3.x + a3.y) + (a3.z + a3.w);
    *(f32x4*)&accbuf[(kseg * 256 + d) * 4] = r;
    __syncthreads();                       // partials visible; h_cur reads done
    if (owner) {
      f32x4 s0 = *(const f32x4*)&accbuf[(0 * 256 + d) * 4];
      f32x4 s1 = *(const f32x4*)&accbuf[(1 * 256 + d) * 4];
      f32x4 s2 = *(const f32x4*)&accbuf[(2 * 256 + d) * 4];
      f32x4 s3 = *(const f32x4*)&accbuf[(3 * 256 + d) * 4];
      f32x4 g = (s0 + s1) + (s2 + s3);
      float gi = g.x + pg0;
      float gf = g.y + pg1;
      float gg = g.z + pg2;
      float go = g.w + pg3;
      float si = 1.f / (1.f + expf(-gi));
      float sf = 1.f / (1.f + expf(-gf));
      float so = 1.f / (1.f + expf(-go));
      float cc = sf * c_st + si * tanhf(gg);
      float hh = so * tanhf(cc);
      c_st = cc;
      h_cur[d] = hh;                       // safe: all h_cur reads were pre-barrier
      hs[(size_t)(t + 1) * 8192 + s * 256 + d] = hh;   // history for k_final
    }
    __syncthreads();                       // new h + accbuf reuse protected
  }
}

// ---------------- final: scores, softmax, BCE, argmax ----------------
__global__ void k_final(const float* __restrict__ hs, const int* __restrict__ mask,
                        const float* __restrict__ labels, const float* __restrict__ W2,
                        const float* __restrict__ b2, float* __restrict__ out) {
  __shared__ float scores[32];
  __shared__ float errpart[8];
  int tid = threadIdx.x;
  if (tid < 32) {
    int len = 0;
    for (int t = 0; t < 128; ++t) len += mask[tid * 128 + t];
    if (len < 1) len = 1;
    const float* hl = hs + (size_t)len * 8192 + tid * 256;
    float acc = b2[0];
    for (int k = 0; k < 256; ++k) acc += hl[k] * W2[k];
    scores[tid] = acc;
  }
  __syncthreads();
  if (tid < 8) {
    float sc[4];
#pragma unroll
    for (int i = 0; i < 4; ++i) sc[i] = scores[tid * 4 + i];
    float mx = fmaxf(fmaxf(sc[0], sc[1]), fmaxf(sc[2], sc[3]));
    float ex[4], ssum = 0.f;
#pragma unroll
    for (int i = 0; i < 4; ++i) { ex[i] = expf(sc[i] - mx); ssum += ex[i]; }
    float esum = 0.f; int am = 0; float best = -1e30f;
#pragma unroll
    for (int i = 0; i < 4; ++i) {
      float p = ex[i] / ssum;
      float li = labels[tid * 4 + i];
      esum += fmaxf(p, 0.f) - p * li + log1pf(expf(-fabsf(p)));
      if (p > best) { best = p; am = i; }
    }
    errpart[tid] = esum;
    out[1 + tid] = (float)am;
  }
  __syncthreads();
  if (tid == 0) {
    float e = 0.f;
    for (int i = 0; i < 8; ++i) e += errpart[i];
    out[0] = e / 32.f;
  }
}

extern "C" void kernel_launch(void* const* d_in, const int* in_sizes, int n_in,
                              void* d_out, int out_size, void* d_ws, size_t ws_size,
                              hipStream_t stream) {
  const int*   input_ids  = (const int*)d_in[0];
  const int*   input_mask = (const int*)d_in[1];
  const float* labels     = (const float*)d_in[2];
  const int*   src        = (const int*)d_in[3];
  const int*   dst        = (const int*)d_in[4];
  const float* ev         = (const float*)d_in[5];
  const float* node_emb   = (const float*)d_in[6];
  const float* W1         = (const float*)d_in[7];
  const float* b1         = (const float*)d_in[8];
  const float* w_ih       = (const float*)d_in[9];
  const float* w_hh       = (const float*)d_in[10];
  const float* b_ih       = (const float*)d_in[11];
  const float* b_hh       = (const float*)d_in[12];
  const float* W2         = (const float*)d_in[13];
  const float* b2         = (const float*)d_in[14];
  float* out = (float*)d_out;
  char* ws = (char*)d_ws;
  int*   slotmap = (int*)(ws + OFF_SLOT);
  float* agg     = (float*)(ws + OFF_AGG);
  float* cnt     = (float*)(ws + OFF_CNT);
  float* Wf      = (float*)(ws + OFF_WF);
  float* biasf   = (float*)(ws + OFF_BIASF);
  float* preg    = (float*)(ws + OFF_PREG);
  float* hs      = (float*)(ws + OFF_HS);

  hipLaunchKernelGGL(k_init,    dim3(2048), dim3(256),  0, stream, slotmap, agg, cnt, hs);
  hipLaunchKernelGGL(k_mark,    dim3(16),   dim3(256),  0, stream, input_ids, slotmap);
  hipLaunchKernelGGL(k_edge,    dim3(6250), dim3(256),  0, stream, src, dst, ev, node_emb, slotmap, agg, cnt);
  hipLaunchKernelGGL(k_div,     dim3(2048), dim3(256),  0, stream, agg, cnt);
  hipLaunchKernelGGL(k_fuse,    dim3(1024), dim3(128),  0, stream, w_ih, W1, b1, b_ih, b_hh, Wf, biasf);
  hipLaunchKernelGGL(k_pregemm, dim3(1024), dim3(256),  0, stream, agg, Wf, biasf, slotmap, input_ids, preg);
  hipLaunchKernelGGL(k_lstm,    dim3(NSEQ), dim3(1024), 0, stream, w_hh, preg, hs);
  hipLaunchKernelGGL(k_final,   dim3(1),    dim3(64),   0, stream, hs, input_mask, labels, W2, b2, out);
}

// Round 5
// 385.376 us; speedup vs baseline: 6.6504x; 6.6504x over previous
//
#include <hip/hip_runtime.h>
#include <math.h>

#define NNODES 100000
#define NEDGES 1600000
#define NPOS   4096      // 32 seqs * 128 steps
#define NSEQ   32
#define TSTEPS 128
#define NB     256       // LSTM blocks: 32 seq-groups x 8 members

typedef float f32x4 __attribute__((ext_vector_type(4)));

// ---- ws layout (bytes) ----
#define OFF_SLOT   0          // int[100000]
#define OFF_AGG    400128     // float[4096*128]
#define OFF_CNT    2497280    // float[4096]
#define OFF_WF     2513664    // float[1024*128]
#define OFF_BIASF  3037952    // float[1024]
#define OFF_PREG   3042048    // float[128][32s][8m][4q][32d]
#define OFF_HS     19819264   // float[129][32][256]

// Exchange buffers in STATIC device memory (module .bss) -- this is ordinary
// COARSE-GRAINED device memory, L2-cacheable. The d_ws workspace is evidently
// fine-grained (R3 fingerprint: +0 atomics produced 103MB of HBM WRITE_SIZE,
// i.e. RMWs forced past L2; R1/R2: sc0 stores bypassed L2 so sc0 polls hit the
// stale zeroed L2 line forever). On coarse-grained memory a non-sc1 atomic
// executes in the LOCAL XCD L2 and a plain store lands dirty in that same L2.
// X: fast same-XCD pairs [32s][2][256]; Y: agent/IF$ mirror (fallback).
__device__ unsigned long long g_ghb[2 * NSEQ * 2 * 256];   // X then Y (256 KiB)
__device__ int g_ctrl[16];                                  // xcd_ctr[8], arrivals, ovf
#define YOFFP (NSEQ * 2 * 256)   // Y offset in 8-byte pairs

// ---------------- init ----------------
__global__ void k_init(int* slotmap, float* agg, float* cnt, float* hs0) {
  int i = blockIdx.x * blockDim.x + threadIdx.x;
  int stride = gridDim.x * blockDim.x;
  for (int idx = i; idx < 4096 * 128; idx += stride) agg[idx] = 0.f;
  for (int idx = i; idx < NNODES; idx += stride) slotmap[idx] = -1;
  for (int idx = i; idx < 4096; idx += stride) cnt[idx] = 0.f;
  for (int idx = i; idx < 8192; idx += stride) hs0[idx] = 0.f;
}

// zero X+Y pair regions + control block -- runs every launch (replay-safe).
// val=0.0f, tag=0  ==> h(0)=0 published for step 0 on both paths. Dirty zero
// lines are flushed at this kernel's end (release), so k_lstm's acquire sees
// clean zeros from any XCD.
__global__ void k_init2() {
  int i = blockIdx.x * blockDim.x + threadIdx.x;
  int stride = gridDim.x * blockDim.x;
  for (int k = i; k < 2 * NSEQ * 2 * 256; k += stride) g_ghb[k] = 0ULL;
  if (i < 16) g_ctrl[i] = 0;
}

// ---------------- mark needed nodes ----------------
__global__ void k_mark(const int* __restrict__ input_ids, int* __restrict__ slotmap) {
  int p = blockIdx.x * blockDim.x + threadIdx.x;
  if (p < NPOS) atomicCAS(&slotmap[input_ids[p]], -1, p);
}

// ---------------- edge pass: masked segment-sum ----------------
__global__ void k_edge(const int* __restrict__ src, const int* __restrict__ dst,
                       const float* __restrict__ ev, const float* __restrict__ emb,
                       const int* __restrict__ slotmap,
                       float* __restrict__ agg, float* __restrict__ cnt) {
  int e = blockIdx.x * 256 + threadIdx.x;
  int lane = threadIdx.x & 63;
  int d = dst[e];
  int slot = slotmap[d];
  int sn = 0; float vv = 0.f;
  if (slot >= 0) { sn = src[e]; vv = ev[e]; }
  unsigned long long m = __ballot(slot >= 0);
  while (m) {
    int j = __ffsll(m) - 1;
    m &= m - 1;
    int sl = __shfl(slot, j);
    int s2 = __shfl(sn, j);
    float v = __shfl(vv, j);
    float2 em = *(const float2*)&emb[(size_t)s2 * 128 + 2 * lane];
    atomicAdd(&agg[sl * 128 + 2 * lane],     em.x * v);
    atomicAdd(&agg[sl * 128 + 2 * lane + 1], em.y * v);
    if (lane == 0) atomicAdd(&cnt[sl], 1.f);
  }
}

// ---------------- divide by count ----------------
__global__ void k_div(float* __restrict__ agg, const float* __restrict__ cnt) {
  int i = blockIdx.x * blockDim.x + threadIdx.x;
  agg[i] /= fmaxf(cnt[i >> 7], 1.f);
}

// ---------------- fuse W_f = w_ih @ W1, bias_f ----------------
__global__ void k_fuse(const float* __restrict__ w_ih, const float* __restrict__ W1,
                       const float* __restrict__ b1, const float* __restrict__ b_ih,
                       const float* __restrict__ b_hh,
                       float* __restrict__ Wf, float* __restrict__ bf) {
  int row = blockIdx.x;
  int e = threadIdx.x;
  float acc = 0.f;
  for (int m2 = 0; m2 < 256; ++m2) acc += w_ih[row * 256 + m2] * W1[m2 * 128 + e];
  Wf[row * 128 + e] = acc;
  if (e == 0) {
    float bacc = b_ih[row] + b_hh[row];
    for (int m2 = 0; m2 < 256; ++m2) bacc += w_ih[row * 256 + m2] * b1[m2];
    bf[row] = bacc;
  }
}

// ---------------- pre-gates GEMM: preg[t][s][m][q][d] ----------------
__global__ __launch_bounds__(256, 2) void k_pregemm(
    const float* __restrict__ hnode, const float* __restrict__ Wf,
    const float* __restrict__ bf, const int* __restrict__ slotmap,
    const int* __restrict__ input_ids, float* __restrict__ preg) {
  __shared__ float Ash[64][132];
  __shared__ float Bsh[64][132];
  __shared__ int slots[64];
  int tid = threadIdx.x;
  int bm = (blockIdx.x & 63) * 64;
  int bn = (blockIdx.x >> 6) * 64;
  if (tid < 64) slots[tid] = slotmap[input_ids[bm + tid]];
  __syncthreads();
#pragma unroll
  for (int i = 0; i < 8; ++i) {
    int idx = tid + 256 * i;
    int r = idx >> 5, c = idx & 31;
    *(float4*)&Ash[r][c * 4] = *(const float4*)&hnode[slots[r] * 128 + c * 4];
    *(float4*)&Bsh[r][c * 4] = *(const float4*)&Wf[(bn + r) * 128 + c * 4];
  }
  __syncthreads();
  int tx = tid & 15, ty = tid >> 4;
  float acc[4][4] = {};
  for (int k = 0; k < 128; k += 4) {
    float4 a[4], bb[4];
#pragma unroll
    for (int i = 0; i < 4; ++i) a[i] = *(const float4*)&Ash[tx + 16 * i][k];
#pragma unroll
    for (int j = 0; j < 4; ++j) bb[j] = *(const float4*)&Bsh[ty + 16 * j][k];
#pragma unroll
    for (int i = 0; i < 4; ++i)
#pragma unroll
      for (int j = 0; j < 4; ++j)
        acc[i][j] += a[i].x * bb[j].x + a[i].y * bb[j].y + a[i].z * bb[j].z + a[i].w * bb[j].w;
  }
#pragma unroll
  for (int j = 0; j < 4; ++j) {
    int row = bn + ty + 16 * j;
    float bias = bf[row];
    int q  = row >> 8;
    int mm = (row >> 5) & 7;
    int dl = row & 31;
#pragma unroll
    for (int i = 0; i < 4; ++i) {
      int p = bm + tx + 16 * i;
      int s = p >> 7, tt = p & 127;
      preg[(((size_t)(tt * 32 + s) * 8 + mm) * 4 + q) * 32 + dl] = acc[i][j] + bias;
    }
  }
}

// ---------------- LSTM: 32 seq-groups x 8 members, L2-local exchange ----------------
// Blocks self-organize by PHYSICAL chiplet (HW_REG_XCC_ID + rank atomics) so all 8
// members of a sequence share one XCD/L2. X lives in STATIC (coarse-grained) device
// memory: producer publishes {f32 h, u32 tag} with a plain store (write-through L1
// -> dirty line in the shared local L2); consumers poll with global_atomic_add_x2
// (+0, sc0, NO sc1): the RMW executes in the local L2 and returns its current copy
// -- sees the same-L2 store regardless of L1 state, no IF$ trip. Y (agent/IF$)
// mirror checked every 8th spin keeps any cross-XCD straggler correct (just slow).
__global__ __launch_bounds__(256, 1) void k_lstm(
    const float* __restrict__ w_hh, const float* __restrict__ preg,
    float* __restrict__ hs) {
  __shared__ float h_lds[512];           // 2 x 256 floats, xor-swizzled
  __shared__ int sh_role;
  int tid = threadIdx.x;

  if (tid == 0) {
    unsigned xcd;
    asm volatile("s_getreg_b32 %0, hwreg(HW_REG_XCC_ID)" : "=s"(xcd));
    xcd &= 7;
    int r = atomicAdd(&g_ctrl[xcd], 1);        // rank within my physical XCD
    int role;
    if (r < 32) {
      role = (int)xcd * 32 + r;
      atomicAdd(&g_ctrl[8], 1);                // arrivals
    } else {
      int o = atomicAdd(&g_ctrl[9], 1);        // overflow rank
      atomicAdd(&g_ctrl[8], 1);
      while (__hip_atomic_load(&g_ctrl[8], __ATOMIC_RELAXED, __HIP_MEMORY_SCOPE_AGENT) < NB) {}
      int acc = 0; role = 0;
      for (int x2 = 0; x2 < 8; ++x2) {
        int c = __hip_atomic_load(&g_ctrl[x2], __ATOMIC_RELAXED, __HIP_MEMORY_SCOPE_AGENT);
        if (c > 32) c = 32;
        int miss = 32 - c;
        if (o >= acc && o < acc + miss) role = x2 * 32 + c + (o - acc);
        acc += miss;
      }
    }
    sh_role = role;
  }
  __syncthreads();
  const int role = sh_role;
  const int s = 4 * (role >> 5) + ((role >> 3) & 3);  // sequence (XCD-local group)
  const int m = role & 7;                             // member: owns dims 32m..32m+31

  int lane = tid & 63, wave = tid >> 6;
  int x = lane & 7, seg = lane >> 3;     // seg 0..7: k-range [32seg, 32seg+32)
  int combo = x + 8 * wave;              // local dim 0..31
  const int isSeg0 = (seg == 0);

  // weights: rows q*256 + 32m + combo, k-slice [32seg, 32seg+32)
  f32x4 wv[4][8];
#pragma unroll
  for (int q = 0; q < 4; ++q) {
    const float* wp = w_hh + (q * 256 + 32 * m + combo) * 256 + seg * 32;
#pragma unroll
    for (int i = 0; i < 8; ++i) wv[q][i] = *(const f32x4*)(wp + 4 * i);
  }

  unsigned long long* xbase = g_ghb + s * 512;   // X: [2][256] pairs
  // swizzled scalar LDS index for dim d = tid (matches f32x4 read pattern)
  int fi = tid >> 2, jj = tid & 3;
  int ldsw = (((fi >> 3) * 8) + ((fi & 7) ^ (fi >> 3))) * 4 + jj;

  float c_st = 0.f;                       // cell state (seg0 lanes)
  unsigned long long z64 = 0ULL;          // atomic add operand

  for (int t = 0; t < TSTEPS; ++t) {
    // poll own pair until tag == t; the value in the same 8B is h[t][tid]
    unsigned long long* px = xbase + (t & 1) * 256 + tid;
    unsigned long long pr;
    int gd = 0;
    for (;;) {
      // L2-executed atomic read (coarse-grained, no sc1 => local XCD L2; sc0 = return old)
      asm volatile("global_atomic_add_x2 %0, %1, %2, off sc0\n\ts_waitcnt vmcnt(0)"
                   : "=v"(pr) : "v"(px), "v"(z64) : "memory");
      if ((unsigned)(pr >> 32) == (unsigned)t) break;
      if ((gd & 7) == 7) {
        pr = __hip_atomic_load(px + YOFFP, __ATOMIC_RELAXED, __HIP_MEMORY_SCOPE_AGENT);
        if ((unsigned)(pr >> 32) == (unsigned)t) break;
      }
      if (++gd >= (1 << 20)) break;
    }
    // prefetch pre-gates AFTER the poll: L2 latency hides under LDS/barrier/dots
    float pg[4] = {0.f, 0.f, 0.f, 0.f};
    if (isSeg0) {
      const float* pb = preg + (((size_t)(t * 32 + s) * 8 + m) * 4) * 32 + combo;
#pragma unroll
      for (int q = 0; q < 4; ++q) pg[q] = pb[q * 32];
    }
    h_lds[(t & 1) * 256 + ldsw] = __uint_as_float((unsigned)pr);
    __syncthreads();
    // partial dots: 4 gate-rows x 32 k per thread
    const f32x4* lds4 = (const f32x4*)(h_lds + (t & 1) * 256);
    float acc[4] = {0.f, 0.f, 0.f, 0.f};
#pragma unroll
    for (int i = 0; i < 8; ++i) {
      f32x4 hv = lds4[seg * 8 + (i ^ seg)];
#pragma unroll
      for (int q = 0; q < 4; ++q)
        acc[q] += wv[q][i].x * hv.x + wv[q][i].y * hv.y
                + wv[q][i].z * hv.z + wv[q][i].w * hv.w;
    }
    // reduce over the 8 k-segments (lane bits 3..5)
#pragma unroll
    for (int q = 0; q < 4; ++q) {
      float v = acc[q];
      v += __shfl_xor(v, 8);
      v += __shfl_xor(v, 16);
      v += __shfl_xor(v, 32);
      acc[q] = v;
    }
    // gate math + tagged publish (seg0 lanes own dim=combo)
    if (isSeg0) {
      float gi = acc[0] + pg[0];
      float gf = acc[1] + pg[1];
      float gg = acc[2] + pg[2];
      float go = acc[3] + pg[3];
      float si = 1.f / (1.f + expf(-gi));
      float sf = 1.f / (1.f + expf(-gf));
      float so = 1.f / (1.f + expf(-go));
      float cc = sf * c_st + si * tanhf(gg);
      float hh = so * tanhf(cc);
      c_st = cc;
      unsigned long long pk =
          ((unsigned long long)(unsigned)(t + 1) << 32) |
          (unsigned long long)__float_as_uint(hh);
      unsigned long long* xp = xbase + ((t + 1) & 1) * 256 + 32 * m + combo;
      // X: plain store -> write-through L1 -> dirty line in the shared XCD L2
      asm volatile("global_store_dwordx2 %0, %1, off"
                   :: "v"(xp), "v"(pk) : "memory");
      // Y: agent-scope mirror (IF$) for cross-XCD stragglers
      __hip_atomic_store(xp + YOFFP, pk, __ATOMIC_RELAXED, __HIP_MEMORY_SCOPE_AGENT);
      hs[(size_t)(t + 1) * 8192 + s * 256 + 32 * m + combo] = hh;  // history
    }
    // no trailing barrier: LDS double-buffer + next-step barrier protect h_lds
  }
}

// ---------------- final: scores, softmax, BCE, argmax ----------------
__global__ void k_final(const float* __restrict__ hs, const int* __restrict__ mask,
                        const float* __restrict__ labels, const float* __restrict__ W2,
                        const float* __restrict__ b2, float* __restrict__ out) {
  __shared__ float scores[32];
  __shared__ float errpart[8];
  int tid = threadIdx.x;
  if (tid < 32) {
    int len = 0;
    for (int t = 0; t < 128; ++t) len += mask[tid * 128 + t];
    if (len < 1) len = 1;
    const float* hl = hs + (size_t)len * 8192 + tid * 256;
    float acc = b2[0];
    for (int k = 0; k < 256; ++k) acc += hl[k] * W2[k];
    scores[tid] = acc;
  }
  __syncthreads();
  if (tid < 8) {
    float sc[4];
#pragma unroll
    for (int i = 0; i < 4; ++i) sc[i] = scores[tid * 4 + i];
    float mx = fmaxf(fmaxf(sc[0], sc[1]), fmaxf(sc[2], sc[3]));
    float ex[4], ssum = 0.f;
#pragma unroll
    for (int i = 0; i < 4; ++i) { ex[i] = expf(sc[i] - mx); ssum += ex[i]; }
    float esum = 0.f; int am = 0; float best = -1e30f;
#pragma unroll
    for (int i = 0; i < 4; ++i) {
      float p = ex[i] / ssum;
      float li = labels[tid * 4 + i];
      esum += fmaxf(p, 0.f) - p * li + log1pf(expf(-fabsf(p)));
      if (p > best) { best = p; am = i; }
    }
    errpart[tid] = esum;
    out[1 + tid] = (float)am;
  }
  __syncthreads();
  if (tid == 0) {
    float e = 0.f;
    for (int i = 0; i < 8; ++i) e += errpart[i];
    out[0] = e / 32.f;
  }
}

extern "C" void kernel_launch(void* const* d_in, const int* in_sizes, int n_in,
                              void* d_out, int out_size, void* d_ws, size_t ws_size,
                              hipStream_t stream) {
  const int*   input_ids  = (const int*)d_in[0];
  const int*   input_mask = (const int*)d_in[1];
  const float* labels     = (const float*)d_in[2];
  const int*   src        = (const int*)d_in[3];
  const int*   dst        = (const int*)d_in[4];
  const float* ev         = (const float*)d_in[5];
  const float* node_emb   = (const float*)d_in[6];
  const float* W1         = (const float*)d_in[7];
  const float* b1         = (const float*)d_in[8];
  const float* w_ih       = (const float*)d_in[9];
  const float* w_hh       = (const float*)d_in[10];
  const float* b_ih       = (const float*)d_in[11];
  const float* b_hh       = (const float*)d_in[12];
  const float* W2         = (const float*)d_in[13];
  const float* b2         = (const float*)d_in[14];
  float* out = (float*)d_out;
  char* ws = (char*)d_ws;
  int*   slotmap = (int*)(ws + OFF_SLOT);
  float* agg     = (float*)(ws + OFF_AGG);
  float* cnt     = (float*)(ws + OFF_CNT);
  float* Wf      = (float*)(ws + OFF_WF);
  float* biasf   = (float*)(ws + OFF_BIASF);
  float* preg    = (float*)(ws + OFF_PREG);
  float* hs      = (float*)(ws + OFF_HS);

  hipLaunchKernelGGL(k_init,    dim3(2048), dim3(256), 0, stream, slotmap, agg, cnt, hs);
  hipLaunchKernelGGL(k_mark,    dim3(16),   dim3(256), 0, stream, input_ids, slotmap);
  hipLaunchKernelGGL(k_edge,    dim3(6250), dim3(256), 0, stream, src, dst, ev, node_emb, slotmap, agg, cnt);
  hipLaunchKernelGGL(k_div,     dim3(2048), dim3(256), 0, stream, agg, cnt);
  hipLaunchKernelGGL(k_fuse,    dim3(1024), dim3(128), 0, stream, w_ih, W1, b1, b_ih, b_hh, Wf, biasf);
  hipLaunchKernelGGL(k_pregemm, dim3(1024), dim3(256), 0, stream, agg, Wf, biasf, slotmap, input_ids, preg);
  hipLaunchKernelGGL(k_init2,   dim3(64),   dim3(256), 0, stream);
  hipLaunchKernelGGL(k_lstm,    dim3(NB),   dim3(256), 0, stream, w_hh, preg, hs);
  hipLaunchKernelGGL(k_final,   dim3(1),    dim3(64),  0, stream, hs, input_mask, labels, W2, b2, out);
}

// Round 6
// 338.001 us; speedup vs baseline: 7.5825x; 1.1402x over previous
//
#include <hip/hip_runtime.h>
#include <math.h>

#define NNODES 100000
#define NEDGES 1600000
#define NPOS   4096      // 32 seqs * 128 steps
#define NSEQ   32
#define TSTEPS 128

typedef float f32x4 __attribute__((ext_vector_type(4)));
typedef unsigned u32x4 __attribute__((ext_vector_type(4)));
typedef _Float16 h2v __attribute__((ext_vector_type(2)));

// ---- ws layout (bytes) ----
#define OFF_SLOT   0          // int[100000]  (dead after k_pregemm)
#define OFF_AGG    400128     // float[4096*128] (dead after k_pregemm; overlaid by wh16)
#define OFF_CNT    2497280    // float[4096]
#define OFF_WF     2513664    // float[1024*128]
#define OFF_BIASF  3037952    // float[1024]
#define OFF_PREG   3042048    // float[128][32s][8m][4q][32d]
#define OFF_HS     19819264   // float[129][32][256]
// fp16 weight images overlay the dead agg region (valid only after k_pregemm):
//   wh16A: u32[192][512]   (gates 0..2, register-resident)   384 KiB
//   wh16L: u32x4[16][512]  (gate 3, LDS-resident)            128 KiB
#define OFF_WH16A  OFF_AGG
#define OFF_WH16L  (OFF_AGG + 192 * 512 * 4)

// fp16 dot2 with f32 accumulate: D = w.h[0]*h.h[0] + w.h[1]*h.h[1] + acc.
// Products are exact in f32 (11-bit mantissas); only input quantization matters.
static __device__ __forceinline__ float fdot2(unsigned w, unsigned h, float acc) {
#if __has_builtin(__builtin_amdgcn_fdot2)
  h2v wv, hv;
  __builtin_memcpy(&wv, &w, 4);
  __builtin_memcpy(&hv, &h, 4);
  return __builtin_amdgcn_fdot2(wv, hv, acc, false);
#else
  asm("v_dot2_f32_f16 %0, %1, %2, %0" : "+v"(acc) : "v"(w), "v"(h));
  return acc;
#endif
}

// ---------------- init ----------------
__global__ void k_init(int* slotmap, float* agg, float* cnt, float* hs0) {
  int i = blockIdx.x * blockDim.x + threadIdx.x;
  int stride = gridDim.x * blockDim.x;
  for (int idx = i; idx < 4096 * 128; idx += stride) agg[idx] = 0.f;
  for (int idx = i; idx < NNODES; idx += stride) slotmap[idx] = -1;
  for (int idx = i; idx < 4096; idx += stride) cnt[idx] = 0.f;
  for (int idx = i; idx < 8192; idx += stride) hs0[idx] = 0.f;
}

// ---------------- mark needed nodes ----------------
__global__ void k_mark(const int* __restrict__ input_ids, int* __restrict__ slotmap) {
  int p = blockIdx.x * blockDim.x + threadIdx.x;
  if (p < NPOS) atomicCAS(&slotmap[input_ids[p]], -1, p);
}

// ---------------- edge pass: masked segment-sum ----------------
__global__ void k_edge(const int* __restrict__ src, const int* __restrict__ dst,
                       const float* __restrict__ ev, const float* __restrict__ emb,
                       const int* __restrict__ slotmap,
                       float* __restrict__ agg, float* __restrict__ cnt) {
  int e = blockIdx.x * 256 + threadIdx.x;
  int lane = threadIdx.x & 63;
  int d = dst[e];
  int slot = slotmap[d];
  int sn = 0; float vv = 0.f;
  if (slot >= 0) { sn = src[e]; vv = ev[e]; }
  unsigned long long m = __ballot(slot >= 0);
  while (m) {
    int j = __ffsll(m) - 1;
    m &= m - 1;
    int sl = __shfl(slot, j);
    int s2 = __shfl(sn, j);
    float v = __shfl(vv, j);
    float2 em = *(const float2*)&emb[(size_t)s2 * 128 + 2 * lane];
    atomicAdd(&agg[sl * 128 + 2 * lane],     em.x * v);
    atomicAdd(&agg[sl * 128 + 2 * lane + 1], em.y * v);
    if (lane == 0) atomicAdd(&cnt[sl], 1.f);
  }
}

// ---------------- divide by count ----------------
__global__ void k_div(float* __restrict__ agg, const float* __restrict__ cnt) {
  int i = blockIdx.x * blockDim.x + threadIdx.x;
  agg[i] /= fmaxf(cnt[i >> 7], 1.f);
}

// ---------------- fuse W_f = w_ih @ W1, bias_f ----------------
__global__ void k_fuse(const float* __restrict__ w_ih, const float* __restrict__ W1,
                       const float* __restrict__ b1, const float* __restrict__ b_ih,
                       const float* __restrict__ b_hh,
                       float* __restrict__ Wf, float* __restrict__ bf) {
  int row = blockIdx.x;
  int e = threadIdx.x;
  float acc = 0.f;
  for (int m2 = 0; m2 < 256; ++m2) acc += w_ih[row * 256 + m2] * W1[m2 * 128 + e];
  Wf[row * 128 + e] = acc;
  if (e == 0) {
    float bacc = b_ih[row] + b_hh[row];
    for (int m2 = 0; m2 < 256; ++m2) bacc += w_ih[row * 256 + m2] * b1[m2];
    bf[row] = bacc;
  }
}

// ---------------- pre-gates GEMM: preg[t][s][m][q][32d] ----------------
__global__ __launch_bounds__(256, 2) void k_pregemm(
    const float* __restrict__ hnode, const float* __restrict__ Wf,
    const float* __restrict__ bf, const int* __restrict__ slotmap,
    const int* __restrict__ input_ids, float* __restrict__ preg) {
  __shared__ float Ash[64][132];
  __shared__ float Bsh[64][132];
  __shared__ int slots[64];
  int tid = threadIdx.x;
  int bm = (blockIdx.x & 63) * 64;
  int bn = (blockIdx.x >> 6) * 64;
  if (tid < 64) slots[tid] = slotmap[input_ids[bm + tid]];
  __syncthreads();
#pragma unroll
  for (int i = 0; i < 8; ++i) {
    int idx = tid + 256 * i;
    int r = idx >> 5, c = idx & 31;
    *(float4*)&Ash[r][c * 4] = *(const float4*)&hnode[slots[r] * 128 + c * 4];
    *(float4*)&Bsh[r][c * 4] = *(const float4*)&Wf[(bn + r) * 128 + c * 4];
  }
  __syncthreads();
  int tx = tid & 15, ty = tid >> 4;
  float acc[4][4] = {};
  for (int k = 0; k < 128; k += 4) {
    float4 a[4], bb[4];
#pragma unroll
    for (int i = 0; i < 4; ++i) a[i] = *(const float4*)&Ash[tx + 16 * i][k];
#pragma unroll
    for (int j = 0; j < 4; ++j) bb[j] = *(const float4*)&Bsh[ty + 16 * j][k];
#pragma unroll
    for (int i = 0; i < 4; ++i)
#pragma unroll
      for (int j = 0; j < 4; ++j)
        acc[i][j] += a[i].x * bb[j].x + a[i].y * bb[j].y + a[i].z * bb[j].z + a[i].w * bb[j].w;
  }
#pragma unroll
  for (int j = 0; j < 4; ++j) {
    int row = bn + ty + 16 * j;
    float bias = bf[row];
    int q  = row >> 8;
    int mm = (row >> 5) & 7;
    int dl = row & 31;
#pragma unroll
    for (int i = 0; i < 4; ++i) {
      int p = bm + tx + 16 * i;
      int s = p >> 7, tt = p & 127;
      preg[(((size_t)(tt * 32 + s) * 8 + mm) * 4 + q) * 32 + dl] = acc[i][j] + bias;
    }
  }
}

// ---------------- w_hh f32 -> packed fp16 images (RNE) ----------------
// Layouts are tailored to k_lstm's thread mapping (tid = kseg*256 + d):
//   gates q=0..2: wh16A[(q*64 + jj)*512 + tid]  (coalesced prologue loads)
//   gate  q=3:    wh16L[((jj>>2)*512 + tid)*4 + (jj&3)]  (b128 LDS slots)
// where pair jj = local pair index 0..63 within the thread's 128-k slice.
__global__ void k_wcvt(const float* __restrict__ w_hh,
                       unsigned* __restrict__ wA, unsigned* __restrict__ wL) {
  int idx = blockIdx.x * 256 + threadIdx.x;   // 0..131071
  int row = idx >> 7;          // 0..1023 : q*256 + d
  int j   = idx & 127;         // global pair index (k = 2j, 2j+1)
  float x0 = w_hh[(size_t)row * 256 + 2 * j];
  float x1 = w_hh[(size_t)row * 256 + 2 * j + 1];
  union { _Float16 f[2]; unsigned u; } pk;
  pk.f[0] = (_Float16)x0;
  pk.f[1] = (_Float16)x1;
  int q = row >> 8, d = row & 255;
  int kseg = j >> 6, jj = j & 63;
  int tid = kseg * 256 + d;
  if (q < 3) {
    wA[(q * 64 + jj) * 512 + tid] = pk.u;
  } else {
    wL[((jj >> 2) * 512 + tid) * 4 + (jj & 3)] = pk.u;
  }
}

// ---------------- LSTM: ONE sequence per CU, fp16 weights, zero communication ----
// R0-R5 proved cross-workgroup signaling bottoms at ~2us/step (memory-side
// coherence point; no L2-local path). R4 proved f32 weights (1MB) cannot be
// CU-resident (RF=512KB). fp16 CAN: 512 threads, 192 packed pairs/thread in
// VGPRs (gates i,f,g) + 64 pairs/thread in LDS (gate o) = 512KB. v_dot2_f32_f16
// keeps the accumulate in f32; preg/c/gates/hs stay f32 -- only the recurrence
// inputs (w, h) are fp16-quantized. Per step: 1024 VALU cyc of dot2 + ~1540 cyc
// LDS weight stream (overlapped) + 2 barriers => ~700ns/step, no polling.
// Thread (kseg=tid>>8, d=tid&255): 4 gate rows {q*256+d}, k-slice
// [128*kseg, 128*kseg+128). kseg partials reduced via LDS; kseg0 owns gates.
__global__ __launch_bounds__(512) void k_lstm(
    const unsigned* __restrict__ wh16A, const unsigned* __restrict__ wh16L,
    const float* __restrict__ preg, float* __restrict__ hs) {
  __shared__ __align__(16) unsigned whL[16 * 512 * 4];  // 128 KiB: gate-o weights
  __shared__ __align__(16) unsigned h16[128];           // 256 fp16 h, packed pairs
  __shared__ __align__(16) float    accb[256 * 4];      // kseg1 partials
  const int tid  = threadIdx.x;
  const int s    = blockIdx.x;
  const int kseg = tid >> 8;
  const int d    = tid & 255;
  const bool owner = (kseg == 0);

  // ---- prologue: weights into VGPRs (gates 0..2) and LDS (gate 3) ----
  unsigned wv[192];
  {
    const unsigned* wa = wh16A + tid;
#pragma unroll
    for (int e = 0; e < 192; ++e) wv[e] = wa[e * 512];   // coalesced
#pragma unroll
    for (int i = 0; i < 16; ++i)
      *(u32x4*)&whL[(i * 512 + tid) * 4] = *(const u32x4*)&wh16L[(i * 512 + tid) * 4];
  }
  if (tid < 128) h16[tid] = 0u;   // h(0) = 0
  float c_st = 0.f;
  __syncthreads();

  const float* pregs = preg + ((size_t)s * 8 + (d >> 5)) * 128 + (d & 31);

  for (int t = 0; t < TSTEPS; ++t) {
    // pre-gates (owners): issue early, consumed after the dots
    float pg0 = 0.f, pg1 = 0.f, pg2 = 0.f, pg3 = 0.f;
    if (owner) {
      const float* pb = pregs + (size_t)t * 32768;   // + t*32*1024
      pg0 = pb[0]; pg1 = pb[32]; pg2 = pb[64]; pg3 = pb[96];
    }
    // ---- partial dots over this thread's 64 pairs (128 k) ----
    float a0 = 0.f, a1 = 0.f, a2 = 0.f, a3 = 0.f;
    const unsigned* hseg = h16 + kseg * 64;
#pragma unroll
    for (int c = 0; c < 16; ++c) {
      u32x4 h4 = *(const u32x4*)(hseg + c * 4);                  // broadcast read
      u32x4 w3 = *(const u32x4*)&whL[(c * 512 + tid) * 4];       // conflict-free b128
#pragma unroll
      for (int k = 0; k < 4; ++k) {
        a0 = fdot2(wv[0 * 64 + c * 4 + k], h4[k], a0);
        a1 = fdot2(wv[1 * 64 + c * 4 + k], h4[k], a1);
        a2 = fdot2(wv[2 * 64 + c * 4 + k], h4[k], a2);
        a3 = fdot2(w3[k],                  h4[k], a3);
      }
    }
    if (!owner) {   // kseg 1: publish partials
      f32x4 r; r.x = a0; r.y = a1; r.z = a2; r.w = a3;
      *(f32x4*)&accb[d * 4] = r;
    }
    __syncthreads();                 // partials visible; h16 reads done
    if (owner) {
      f32x4 r = *(const f32x4*)&accb[d * 4];
      float gi = a0 + r.x + pg0;
      float gf = a1 + r.y + pg1;
      float gg = a2 + r.z + pg2;
      float go = a3 + r.w + pg3;
      float si = 1.f / (1.f + expf(-gi));
      float sf = 1.f / (1.f + expf(-gf));
      float so = 1.f / (1.f + expf(-go));
      float cc = sf * c_st + si * tanhf(gg);
      float hh = so * tanhf(cc);
      c_st = cc;
      ((_Float16*)h16)[d] = (_Float16)hh;                    // next-step h (fp16)
      hs[(size_t)(t + 1) * 8192 + s * 256 + d] = hh;         // f32 history
    }
    __syncthreads();                 // new h16 + accb reuse protected
  }
}

// ---------------- final: scores, softmax, BCE, argmax ----------------
__global__ void k_final(const float* __restrict__ hs, const int* __restrict__ mask,
                        const float* __restrict__ labels, const float* __restrict__ W2,
                        const float* __restrict__ b2, float* __restrict__ out) {
  __shared__ float scores[32];
  __shared__ float errpart[8];
  int tid = threadIdx.x;
  if (tid < 32) {
    int len = 0;
    for (int t = 0; t < 128; ++t) len += mask[tid * 128 + t];
    if (len < 1) len = 1;
    const float* hl = hs + (size_t)len * 8192 + tid * 256;
    float acc = b2[0];
    for (int k = 0; k < 256; ++k) acc += hl[k] * W2[k];
    scores[tid] = acc;
  }
  __syncthreads();
  if (tid < 8) {
    float sc[4];
#pragma unroll
    for (int i = 0; i < 4; ++i) sc[i] = scores[tid * 4 + i];
    float mx = fmaxf(fmaxf(sc[0], sc[1]), fmaxf(sc[2], sc[3]));
    float ex[4], ssum = 0.f;
#pragma unroll
    for (int i = 0; i < 4; ++i) { ex[i] = expf(sc[i] - mx); ssum += ex[i]; }
    float esum = 0.f; int am = 0; float best = -1e30f;
#pragma unroll
    for (int i = 0; i < 4; ++i) {
      float p = ex[i] / ssum;
      float li = labels[tid * 4 + i];
      esum += fmaxf(p, 0.f) - p * li + log1pf(expf(-fabsf(p)));
      if (p > best) { best = p; am = i; }
    }
    errpart[tid] = esum;
    out[1 + tid] = (float)am;
  }
  __syncthreads();
  if (tid == 0) {
    float e = 0.f;
    for (int i = 0; i < 8; ++i) e += errpart[i];
    out[0] = e / 32.f;
  }
}

extern "C" void kernel_launch(void* const* d_in, const int* in_sizes, int n_in,
                              void* d_out, int out_size, void* d_ws, size_t ws_size,
                              hipStream_t stream) {
  const int*   input_ids  = (const int*)d_in[0];
  const int*   input_mask = (const int*)d_in[1];
  const float* labels     = (const float*)d_in[2];
  const int*   src        = (const int*)d_in[3];
  const int*   dst        = (const int*)d_in[4];
  const float* ev         = (const float*)d_in[5];
  const float* node_emb   = (const float*)d_in[6];
  const float* W1         = (const float*)d_in[7];
  const float* b1         = (const float*)d_in[8];
  const float* w_ih       = (const float*)d_in[9];
  const float* w_hh       = (const float*)d_in[10];
  const float* b_ih       = (const float*)d_in[11];
  const float* b_hh       = (const float*)d_in[12];
  const float* W2         = (const float*)d_in[13];
  const float* b2         = (const float*)d_in[14];
  float* out = (float*)d_out;
  char* ws = (char*)d_ws;
  int*      slotmap = (int*)(ws + OFF_SLOT);
  float*    agg     = (float*)(ws + OFF_AGG);
  float*    cnt     = (float*)(ws + OFF_CNT);
  float*    Wf      = (float*)(ws + OFF_WF);
  float*    biasf   = (float*)(ws + OFF_BIASF);
  float*    preg    = (float*)(ws + OFF_PREG);
  float*    hs      = (float*)(ws + OFF_HS);
  unsigned* wh16A   = (unsigned*)(ws + OFF_WH16A);
  unsigned* wh16L   = (unsigned*)(ws + OFF_WH16L);

  hipLaunchKernelGGL(k_init,    dim3(2048), dim3(256), 0, stream, slotmap, agg, cnt, hs);
  hipLaunchKernelGGL(k_mark,    dim3(16),   dim3(256), 0, stream, input_ids, slotmap);
  hipLaunchKernelGGL(k_edge,    dim3(6250), dim3(256), 0, stream, src, dst, ev, node_emb, slotmap, agg, cnt);
  hipLaunchKernelGGL(k_div,     dim3(2048), dim3(256), 0, stream, agg, cnt);
  hipLaunchKernelGGL(k_fuse,    dim3(1024), dim3(128), 0, stream, w_ih, W1, b1, b_ih, b_hh, Wf, biasf);
  hipLaunchKernelGGL(k_pregemm, dim3(1024), dim3(256), 0, stream, agg, Wf, biasf, slotmap, input_ids, preg);
  hipLaunchKernelGGL(k_wcvt,    dim3(512),  dim3(256), 0, stream, w_hh, wh16A, wh16L);
  hipLaunchKernelGGL(k_lstm,    dim3(NSEQ), dim3(512), 0, stream, wh16A, wh16L, preg, hs);
  hipLaunchKernelGGL(k_final,   dim3(1),    dim3(64),  0, stream, hs, input_mask, labels, W2, b2, out);
}

// Round 7
// 336.682 us; speedup vs baseline: 7.6122x; 1.0039x over previous
//
#include <hip/hip_runtime.h>
#include <math.h>

#define NNODES 100000
#define NEDGES 1600000
#define NPOS   4096      // 32 seqs * 128 steps
#define NSEQ   32
#define TSTEPS 128

typedef float f32x4 __attribute__((ext_vector_type(4)));
typedef unsigned u32x4 __attribute__((ext_vector_type(4)));
typedef _Float16 h2v __attribute__((ext_vector_type(2)));

// ---- ws layout (bytes) ----
#define OFF_SLOT   0          // int[100000]  (dead after k_pregemm)
#define OFF_AGG    400128     // float[4096*128] (dead after k_pregemm; overlaid by wh16)
#define OFF_CNT    2497280    // float[4096]
#define OFF_WF     2513664    // float[1024*128]
#define OFF_BIASF  3037952    // float[1024]
#define OFF_PREG   3042048    // float[128][32s][8m][4q][32d]
#define OFF_HS     19819264   // float[129][32][256]
// fp16 weight images overlay the dead agg region (valid only after k_pregemm):
//   wh16A: u32[192][512]   (gates 0..2, register-resident)   384 KiB
//   wh16L: u32x4[16][512]  (gate 3, LDS-resident)            128 KiB
#define OFF_WH16A  OFF_AGG
#define OFF_WH16L  (OFF_AGG + 192 * 512 * 4)

// fp16 dot2 with f32 accumulate: D = w.h[0]*h.h[0] + w.h[1]*h.h[1] + acc.
// Products are exact in f32 (11-bit mantissas); only input quantization matters.
static __device__ __forceinline__ float fdot2(unsigned w, unsigned h, float acc) {
#if __has_builtin(__builtin_amdgcn_fdot2)
  h2v wv, hv;
  __builtin_memcpy(&wv, &w, 4);
  __builtin_memcpy(&hv, &h, 4);
  return __builtin_amdgcn_fdot2(wv, hv, acc, false);
#else
  asm("v_dot2_f32_f16 %0, %1, %2, %0" : "+v"(acc) : "v"(w), "v"(h));
  return acc;
#endif
}

// ---------------- init ----------------
__global__ void k_init(int* slotmap, float* agg, float* cnt, float* hs0) {
  int i = blockIdx.x * blockDim.x + threadIdx.x;
  int stride = gridDim.x * blockDim.x;
  for (int idx = i; idx < 4096 * 128; idx += stride) agg[idx] = 0.f;
  for (int idx = i; idx < NNODES; idx += stride) slotmap[idx] = -1;
  for (int idx = i; idx < 4096; idx += stride) cnt[idx] = 0.f;
  for (int idx = i; idx < 8192; idx += stride) hs0[idx] = 0.f;
}

// ---------------- mark needed nodes ----------------
__global__ void k_mark(const int* __restrict__ input_ids, int* __restrict__ slotmap) {
  int p = blockIdx.x * blockDim.x + threadIdx.x;
  if (p < NPOS) atomicCAS(&slotmap[input_ids[p]], -1, p);
}

// ---------------- edge pass: masked segment-sum ----------------
__global__ void k_edge(const int* __restrict__ src, const int* __restrict__ dst,
                       const float* __restrict__ ev, const float* __restrict__ emb,
                       const int* __restrict__ slotmap,
                       float* __restrict__ agg, float* __restrict__ cnt) {
  int e = blockIdx.x * 256 + threadIdx.x;
  int lane = threadIdx.x & 63;
  int d = dst[e];
  int slot = slotmap[d];
  int sn = 0; float vv = 0.f;
  if (slot >= 0) { sn = src[e]; vv = ev[e]; }
  unsigned long long m = __ballot(slot >= 0);
  while (m) {
    int j = __ffsll(m) - 1;
    m &= m - 1;
    int sl = __shfl(slot, j);
    int s2 = __shfl(sn, j);
    float v = __shfl(vv, j);
    float2 em = *(const float2*)&emb[(size_t)s2 * 128 + 2 * lane];
    atomicAdd(&agg[sl * 128 + 2 * lane],     em.x * v);
    atomicAdd(&agg[sl * 128 + 2 * lane + 1], em.y * v);
    if (lane == 0) atomicAdd(&cnt[sl], 1.f);
  }
}

// ---------------- divide by count ----------------
__global__ void k_div(float* __restrict__ agg, const float* __restrict__ cnt) {
  int i = blockIdx.x * blockDim.x + threadIdx.x;
  agg[i] /= fmaxf(cnt[i >> 7], 1.f);
}

// ---------------- fuse W_f = w_ih @ W1, bias_f ----------------
__global__ void k_fuse(const float* __restrict__ w_ih, const float* __restrict__ W1,
                       const float* __restrict__ b1, const float* __restrict__ b_ih,
                       const float* __restrict__ b_hh,
                       float* __restrict__ Wf, float* __restrict__ bf) {
  int row = blockIdx.x;
  int e = threadIdx.x;
  float acc = 0.f;
  for (int m2 = 0; m2 < 256; ++m2) acc += w_ih[row * 256 + m2] * W1[m2 * 128 + e];
  Wf[row * 128 + e] = acc;
  if (e == 0) {
    float bacc = b_ih[row] + b_hh[row];
    for (int m2 = 0; m2 < 256; ++m2) bacc += w_ih[row * 256 + m2] * b1[m2];
    bf[row] = bacc;
  }
}

// ---------------- pre-gates GEMM: preg[t][s][m][q][32d] ----------------
__global__ __launch_bounds__(256, 2) void k_pregemm(
    const float* __restrict__ hnode, const float* __restrict__ Wf,
    const float* __restrict__ bf, const int* __restrict__ slotmap,
    const int* __restrict__ input_ids, float* __restrict__ preg) {
  __shared__ float Ash[64][132];
  __shared__ float Bsh[64][132];
  __shared__ int slots[64];
  int tid = threadIdx.x;
  int bm = (blockIdx.x & 63) * 64;
  int bn = (blockIdx.x >> 6) * 64;
  if (tid < 64) slots[tid] = slotmap[input_ids[bm + tid]];
  __syncthreads();
#pragma unroll
  for (int i = 0; i < 8; ++i) {
    int idx = tid + 256 * i;
    int r = idx >> 5, c = idx & 31;
    *(float4*)&Ash[r][c * 4] = *(const float4*)&hnode[slots[r] * 128 + c * 4];
    *(float4*)&Bsh[r][c * 4] = *(const float4*)&Wf[(bn + r) * 128 + c * 4];
  }
  __syncthreads();
  int tx = tid & 15, ty = tid >> 4;
  float acc[4][4] = {};
  for (int k = 0; k < 128; k += 4) {
    float4 a[4], bb[4];
#pragma unroll
    for (int i = 0; i < 4; ++i) a[i] = *(const float4*)&Ash[tx + 16 * i][k];
#pragma unroll
    for (int j = 0; j < 4; ++j) bb[j] = *(const float4*)&Bsh[ty + 16 * j][k];
#pragma unroll
    for (int i = 0; i < 4; ++i)
#pragma unroll
      for (int j = 0; j < 4; ++j)
        acc[i][j] += a[i].x * bb[j].x + a[i].y * bb[j].y + a[i].z * bb[j].z + a[i].w * bb[j].w;
  }
#pragma unroll
  for (int j = 0; j < 4; ++j) {
    int row = bn + ty + 16 * j;
    float bias = bf[row];
    int q  = row >> 8;
    int mm = (row >> 5) & 7;
    int dl = row & 31;
#pragma unroll
    for (int i = 0; i < 4; ++i) {
      int p = bm + tx + 16 * i;
      int s = p >> 7, tt = p & 127;
      preg[(((size_t)(tt * 32 + s) * 8 + mm) * 4 + q) * 32 + dl] = acc[i][j] + bias;
    }
  }
}

// ---------------- w_hh f32 -> packed fp16 images (RNE) ----------------
// Layouts are tailored to k_lstm's thread mapping (tid = kseg*256 + d):
//   gates q=0..2: wh16A[(q*64 + jj)*512 + tid]  (coalesced prologue loads)
//   gate  q=3:    wh16L[((jj>>2)*512 + tid)*4 + (jj&3)]  (b128 LDS slots)
// where pair jj = local pair index 0..63 within the thread's 128-k slice.
__global__ void k_wcvt(const float* __restrict__ w_hh,
                       unsigned* __restrict__ wA, unsigned* __restrict__ wL) {
  int idx = blockIdx.x * 256 + threadIdx.x;   // 0..131071
  int row = idx >> 7;          // 0..1023 : q*256 + d
  int j   = idx & 127;         // global pair index (k = 2j, 2j+1)
  float x0 = w_hh[(size_t)row * 256 + 2 * j];
  float x1 = w_hh[(size_t)row * 256 + 2 * j + 1];
  union { _Float16 f[2]; unsigned u; } pk;
  pk.f[0] = (_Float16)x0;
  pk.f[1] = (_Float16)x1;
  int q = row >> 8, d = row & 255;
  int kseg = j >> 6, jj = j & 63;
  int tid = kseg * 256 + d;
  if (q < 3) {
    wA[(q * 64 + jj) * 512 + tid] = pk.u;
  } else {
    wL[((jj >> 2) * 512 + tid) * 4 + (jj & 3)] = pk.u;
  }
}

// ---------------- LSTM: ONE sequence per CU, fp16 weights, zero communication ----
// R6 post-mortem: __launch_bounds__(512) defaulted the VGPR cap to 128, so the
// wv[192] weight array spilled to scratch and was re-streamed every step
// (VGPR_Count=128, VALUBusy 8%, 1.62us/step). The block is 8 waves = 2/SIMD;
// the SIMD RF (512 wave-registers) physically allows 256 VGPRs/wave at that
// occupancy. __launch_bounds__(512, 2) (min 2 waves/EU) raises the cap to 256
// => wv[192] (+~40 working regs) is genuinely register-resident.
// Per step: 256 dot2/thread (2 waves/SIMD -> 1024 cyc = 427ns) + LDS gate-o
// stream + 2 barriers + owner gate math => ~0.6-0.8us/step target.
__global__ __launch_bounds__(512, 2) void k_lstm(
    const unsigned* __restrict__ wh16A, const unsigned* __restrict__ wh16L,
    const float* __restrict__ preg, float* __restrict__ hs) {
  __shared__ __align__(16) unsigned whL[16 * 512 * 4];  // 128 KiB: gate-o weights
  __shared__ __align__(16) unsigned h16[128];           // 256 fp16 h, packed pairs
  __shared__ __align__(16) float    accb[256 * 4];      // kseg1 partials
  const int tid  = threadIdx.x;
  const int s    = blockIdx.x;
  const int kseg = tid >> 8;
  const int d    = tid & 255;
  const bool owner = (kseg == 0);

  // ---- prologue: weights into VGPRs (gates 0..2) and LDS (gate 3) ----
  unsigned wv[192];
  {
    const unsigned* wa = wh16A + tid;
#pragma unroll
    for (int e = 0; e < 192; ++e) wv[e] = wa[e * 512];   // coalesced
#pragma unroll
    for (int i = 0; i < 16; ++i)
      *(u32x4*)&whL[(i * 512 + tid) * 4] = *(const u32x4*)&wh16L[(i * 512 + tid) * 4];
  }
  if (tid < 128) h16[tid] = 0u;   // h(0) = 0
  float c_st = 0.f;
  __syncthreads();

  const float* pregs = preg + ((size_t)s * 8 + (d >> 5)) * 128 + (d & 31);

  for (int t = 0; t < TSTEPS; ++t) {
    // pre-gates (owners): issue early, consumed after the dots
    float pg0 = 0.f, pg1 = 0.f, pg2 = 0.f, pg3 = 0.f;
    if (owner) {
      const float* pb = pregs + (size_t)t * 32768;   // + t*32*1024
      pg0 = pb[0]; pg1 = pb[32]; pg2 = pb[64]; pg3 = pb[96];
    }
    // ---- partial dots over this thread's 64 pairs (128 k) ----
    float a0 = 0.f, a1 = 0.f, a2 = 0.f, a3 = 0.f;
    const unsigned* hseg = h16 + kseg * 64;
#pragma unroll
    for (int c = 0; c < 16; ++c) {
      u32x4 h4 = *(const u32x4*)(hseg + c * 4);                  // broadcast read
      u32x4 w3 = *(const u32x4*)&whL[(c * 512 + tid) * 4];       // conflict-free b128
#pragma unroll
      for (int k = 0; k < 4; ++k) {
        a0 = fdot2(wv[0 * 64 + c * 4 + k], h4[k], a0);
        a1 = fdot2(wv[1 * 64 + c * 4 + k], h4[k], a1);
        a2 = fdot2(wv[2 * 64 + c * 4 + k], h4[k], a2);
        a3 = fdot2(w3[k],                  h4[k], a3);
      }
    }
    if (!owner) {   // kseg 1: publish partials
      f32x4 r; r.x = a0; r.y = a1; r.z = a2; r.w = a3;
      *(f32x4*)&accb[d * 4] = r;
    }
    __syncthreads();                 // partials visible; h16 reads done
    if (owner) {
      f32x4 r = *(const f32x4*)&accb[d * 4];
      float gi = a0 + r.x + pg0;
      float gf = a1 + r.y + pg1;
      float gg = a2 + r.z + pg2;
      float go = a3 + r.w + pg3;
      float si = 1.f / (1.f + expf(-gi));
      float sf = 1.f / (1.f + expf(-gf));
      float so = 1.f / (1.f + expf(-go));
      float cc = sf * c_st + si * tanhf(gg);
      float hh = so * tanhf(cc);
      c_st = cc;
      ((_Float16*)h16)[d] = (_Float16)hh;                    // next-step h (fp16)
      hs[(size_t)(t + 1) * 8192 + s * 256 + d] = hh;         // f32 history
    }
    __syncthreads();                 // new h16 + accb reuse protected
  }
}

// ---------------- final: scores, softmax, BCE, argmax ----------------
__global__ void k_final(const float* __restrict__ hs, const int* __restrict__ mask,
                        const float* __restrict__ labels, const float* __restrict__ W2,
                        const float* __restrict__ b2, float* __restrict__ out) {
  __shared__ float scores[32];
  __shared__ float errpart[8];
  int tid = threadIdx.x;
  if (tid < 32) {
    int len = 0;
    for (int t = 0; t < 128; ++t) len += mask[tid * 128 + t];
    if (len < 1) len = 1;
    const float* hl = hs + (size_t)len * 8192 + tid * 256;
    float acc = b2[0];
    for (int k = 0; k < 256; ++k) acc += hl[k] * W2[k];
    scores[tid] = acc;
  }
  __syncthreads();
  if (tid < 8) {
    float sc[4];
#pragma unroll
    for (int i = 0; i < 4; ++i) sc[i] = scores[tid * 4 + i];
    float mx = fmaxf(fmaxf(sc[0], sc[1]), fmaxf(sc[2], sc[3]));
    float ex[4], ssum = 0.f;
#pragma unroll
    for (int i = 0; i < 4; ++i) { ex[i] = expf(sc[i] - mx); ssum += ex[i]; }
    float esum = 0.f; int am = 0; float best = -1e30f;
#pragma unroll
    for (int i = 0; i < 4; ++i) {
      float p = ex[i] / ssum;
      float li = labels[tid * 4 + i];
      esum += fmaxf(p, 0.f) - p * li + log1pf(expf(-fabsf(p)));
      if (p > best) { best = p; am = i; }
    }
    errpart[tid] = esum;
    out[1 + tid] = (float)am;
  }
  __syncthreads();
  if (tid == 0) {
    float e = 0.f;
    for (int i = 0; i < 8; ++i) e += errpart[i];
    out[0] = e / 32.f;
  }
}

extern "C" void kernel_launch(void* const* d_in, const int* in_sizes, int n_in,
                              void* d_out, int out_size, void* d_ws, size_t ws_size,
                              hipStream_t stream) {
  const int*   input_ids  = (const int*)d_in[0];
  const int*   input_mask = (const int*)d_in[1];
  const float* labels     = (const float*)d_in[2];
  const int*   src        = (const int*)d_in[3];
  const int*   dst        = (const int*)d_in[4];
  const float* ev         = (const float*)d_in[5];
  const float* node_emb   = (const float*)d_in[6];
  const float* W1         = (const float*)d_in[7];
  const float* b1         = (const float*)d_in[8];
  const float* w_ih       = (const float*)d_in[9];
  const float* w_hh       = (const float*)d_in[10];
  const float* b_ih       = (const float*)d_in[11];
  const float* b_hh       = (const float*)d_in[12];
  const float* W2         = (const float*)d_in[13];
  const float* b2         = (const float*)d_in[14];
  float* out = (float*)d_out;
  char* ws = (char*)d_ws;
  int*      slotmap = (int*)(ws + OFF_SLOT);
  float*    agg     = (float*)(ws + OFF_AGG);
  float*    cnt     = (float*)(ws + OFF_CNT);
  float*    Wf      = (float*)(ws + OFF_WF);
  float*    biasf   = (float*)(ws + OFF_BIASF);
  float*    preg    = (float*)(ws + OFF_PREG);
  float*    hs      = (float*)(ws + OFF_HS);
  unsigned* wh16A   = (unsigned*)(ws + OFF_WH16A);
  unsigned* wh16L   = (unsigned*)(ws + OFF_WH16L);

  hipLaunchKernelGGL(k_init,    dim3(2048), dim3(256), 0, stream, slotmap, agg, cnt, hs);
  hipLaunchKernelGGL(k_mark,    dim3(16),   dim3(256), 0, stream, input_ids, slotmap);
  hipLaunchKernelGGL(k_edge,    dim3(6250), dim3(256), 0, stream, src, dst, ev, node_emb, slotmap, agg, cnt);
  hipLaunchKernelGGL(k_div,     dim3(2048), dim3(256), 0, stream, agg, cnt);
  hipLaunchKernelGGL(k_fuse,    dim3(1024), dim3(128), 0, stream, w_ih, W1, b1, b_ih, b_hh, Wf, biasf);
  hipLaunchKernelGGL(k_pregemm, dim3(1024), dim3(256), 0, stream, agg, Wf, biasf, slotmap, input_ids, preg);
  hipLaunchKernelGGL(k_wcvt,    dim3(512),  dim3(256), 0, stream, w_hh, wh16A, wh16L);
  hipLaunchKernelGGL(k_lstm,    dim3(NSEQ), dim3(512), 0, stream, wh16A, wh16L, preg, hs);
  hipLaunchKernelGGL(k_final,   dim3(1),    dim3(64),  0, stream, hs, input_mask, labels, W2, b2, out);
}